// Round 6
// baseline (15430.098 us; speedup 1.0000x reference)
//
#include <hip/hip_runtime.h>
#include <math.h>

#define TT 32
#define DD 64
#define NN 1024
#define VV 64
#define RR 4
#define HH 512
#define NT 1024
#define NB 256

typedef unsigned int uint_t;
typedef unsigned short ushort_t;

__device__ __forceinline__ float sigf(float x) { return 1.0f / (1.0f + __expf(-x)); }
__device__ __forceinline__ float splus(float x) {
  return (x > 0.f) ? (x + log1pf(__expf(-x))) : log1pf(__expf(x));
}
__device__ __forceinline__ float dot4f(float4 a, float4 b) {
  return a.x * b.x + a.y * b.y + a.z * b.z + a.w * b.w;
}
__device__ __forceinline__ ushort_t bfr(float f) {
  uint_t u = __float_as_uint(f);
  return (ushort_t)((u + 0x7fffu + ((u >> 16) & 1u)) >> 16);
}
__device__ __forceinline__ float bflo(uint_t u) { return __uint_as_float(u << 16); }
__device__ __forceinline__ float bfhi(uint_t u) { return __uint_as_float(u & 0xffff0000u); }

// A staging buffer: k-major quads. A[k][b] lives at ((k>>2)*64 + b)*4 + (k&3).
__device__ __forceinline__ void Aw(float* g_A, int k, int b, float v) {
  g_A[(((size_t)(k >> 2)) * 64 + b) * 4 + (k & 3)] = v;
}

// 256-block grid barrier (monotonic epoch; counter zeroed each launch).
__device__ __forceinline__ void gbar(uint_t* cnt, int epoch, int tid) {
  __syncthreads();
  if (tid == 0) {
    __threadfence();
    atomicAdd(cnt, 1u);
    uint_t tgt = (uint_t)(NB * epoch);
    while (__hip_atomic_load(cnt, __ATOMIC_RELAXED, __HIP_MEMORY_SCOPE_AGENT) < tgt)
      __builtin_amdgcn_s_sleep(2);
    __threadfence();
  }
  __syncthreads();
}

// NTM addressing softmax chain (content -> interp -> shift -> sharpen).
// All 1024 threads of a batch-block call; 3 internal syncs; returns final w (own row),
// updates s_ws_slot[tid].
__device__ __forceinline__ float soft_addr(
    float dotv, float kk, float beta_raw, float g_raw, float sh0, float sh1,
    float sh2, float gam_raw, float na, float* __restrict__ s_ws_slot,
    float* __restrict__ s_scr, float* __restrict__ s_red, int tid, int lane, int wave) {
  float nb = fmaxf(sqrtf(kk), 1e-8f);
  float beta = splus(beta_raw);
  float g = sigf(g_raw);
  float mx = fmaxf(sh0, fmaxf(sh1, sh2));
  float e0 = __expf(sh0 - mx), e1 = __expf(sh1 - mx), e2 = __expf(sh2 - mx);
  float sinv = 1.0f / (e0 + e1 + e2);
  float gamma = 1.0f + splus(gam_raw);
  float z = beta * dotv / (na * nb);
  float ee = __expf(z);                 // |z| <= beta: no max-subtract needed
  float v = ee;
  #pragma unroll
  for (int o = 32; o; o >>= 1) v += __shfl_xor(v, o);
  if (lane == 0) s_red[wave] = v;
  __syncthreads();
  float S = 0.f;
  #pragma unroll
  for (int w = 0; w < 16; ++w) S += s_red[w];
  float wgv = g * (ee / S) + (1.0f - g) * s_ws_slot[tid];
  s_scr[1024 + tid] = wgv;
  __syncthreads();
  const float* wg = s_scr + 1024;
  float wsn = (e0 * sinv) * wg[(tid + 1023) & 1023] + (e1 * sinv) * wg[tid] +
              (e2 * sinv) * wg[(tid + 1) & 1023];
  float wp = __expf(gamma * __logf(wsn));
  v = wp;
  #pragma unroll
  for (int o = 32; o; o >>= 1) v += __shfl_xor(v, o);
  if (lane == 0) s_red[wave] = v;
  __syncthreads();
  float Z = 0.f;
  #pragma unroll
  for (int w = 0; w < 16; ++w) Z += s_red[w];
  float wfin = wp / (Z + 1e-16f);
  s_ws_slot[tid] = wfin;
  return wfin;
}

__global__ __launch_bounds__(NT, 8) void ntm_fwd(
    const float* __restrict__ x, const float* __restrict__ mem_bias,
    const float* __restrict__ h_bias, const float* __restrict__ c_bias,
    const float* __restrict__ W_ih, const float* __restrict__ W_hh,
    const float* __restrict__ gbias,
    const float* __restrict__ read_W, const float* __restrict__ read_b,
    const float* __restrict__ write_W, const float* __restrict__ write_b,
    const float* __restrict__ read_init,
    const float* __restrict__ out_W, const float* __restrict__ out_b,
    float* __restrict__ out,
    ushort_t* __restrict__ g_mem, float* __restrict__ g_A,
    float* __restrict__ g_gates, float* __restrict__ g_headp,
    float* __restrict__ g_outp, uint_t* __restrict__ g_cnt) {
  const int blk = blockIdx.x;
  const int tid = threadIdx.x;
  const int lane = tid & 63;          // GEMM phases: lane = batch column
  const int wave = tid >> 6;
  const int wid = blk * 16 + wave;
  const bool isBatch = (blk < 64);
  const int b2 = blk;                 // batch id for batch-blocks
  int epoch = 0;

  __shared__ float s_ws[8 * NN];                // shift-weight history, 32 KB
  __shared__ alignas(16) float s_scr[2048];     // w[0:1024] | wg/einsum partials
  __shared__ float s_c[HH];
  __shared__ alignas(16) float s_reads[RR * VV];
  __shared__ alignas(16) float s_or[80];
  __shared__ alignas(16) float s_ow[200];
  __shared__ alignas(16) float s_e[VV];
  __shared__ alignas(16) float s_a[VV];
  __shared__ float s_redR[16];
  __shared__ float s_redW[16];

  ushort_t* membf = g_mem + (size_t)b2 * (NN * VV);
  float nrm2 = 0.f;                   // own-row |mem|^2, thread-persistent

  // ---- init ----
  if (isBatch) {
    if (tid < DD) Aw(g_A, tid, b2, x[((size_t)b2 * TT) * DD + tid]);
    else if (tid < 320) Aw(g_A, tid, b2, read_init[tid - 64]);
    else if (tid < 832) Aw(g_A, tid, b2, h_bias[tid - 320]);
    if (tid < HH) s_c[tid] = c_bias[tid];
    for (int i = tid; i < 8 * NN; i += NT) s_ws[i] = 0.0f;
    const float4* src = (const float4*)(mem_bias + (size_t)tid * VV);
    uint4* dst = (uint4*)(membf + (size_t)tid * VV);
    #pragma unroll
    for (int p = 0; p < 8; ++p) {
      float4 va = src[2 * p], vb = src[2 * p + 1];
      uint4 o;
      o.x = (uint_t)bfr(va.x) | ((uint_t)bfr(va.y) << 16);
      o.y = (uint_t)bfr(va.z) | ((uint_t)bfr(va.w) << 16);
      o.z = (uint_t)bfr(vb.x) | ((uint_t)bfr(vb.y) << 16);
      o.w = (uint_t)bfr(vb.z) | ((uint_t)bfr(vb.w) << 16);
      dst[p] = o;
      float r0 = bflo(o.x), r1 = bfhi(o.x), r2 = bflo(o.y), r3 = bfhi(o.y);
      float r4 = bflo(o.z), r5 = bfhi(o.z), r6 = bflo(o.w), r7 = bfhi(o.w);
      nrm2 += r0 * r0 + r1 * r1 + r2 * r2 + r3 * r3 +
              r4 * r4 + r5 * r5 + r6 * r6 + r7 * r7;
    }
  }
  gbar(g_cnt, ++epoch, tid);

  for (int t = 0; t <= TT; ++t) {
    // ======== phase A: GEMM1 (gates_t for t<32; out_{t-1} partials for t>0) ========
    if (t < TT) {
      int jj = __builtin_amdgcn_readfirstlane(wid >> 1);
      int kh = wid & 1;
      const float4* A4 = (const float4*)g_A;
      float acc;
      if (kh == 0) {
        const float4* W4 = (const float4*)(W_ih + (size_t)jj * 320);
        acc = gbias[jj];
        #pragma unroll 4
        for (int p = 0; p < 80; ++p) acc += dot4f(W4[p], A4[(size_t)p * 64 + lane]);
      } else {
        const float4* W4 = (const float4*)(W_hh + (size_t)jj * 512);
        acc = 0.f;
        #pragma unroll 4
        for (int p = 0; p < 128; ++p) acc += dot4f(W4[p], A4[(size_t)(80 + p) * 64 + lane]);
      }
      g_gates[(size_t)kh * 131072 + (size_t)jj * 64 + lane] = acc;
    }
    if (t > 0 && wave == 0 && blk < 128) {
      int j = blk >> 1, kh = blk & 1;
      const float4* Wo = (const float4*)(out_W + (size_t)j * 768);
      const float4* A4 = (const float4*)g_A;
      float acc;
      if (kh == 0) {
        acc = out_b[j];
        #pragma unroll 4
        for (int p = 0; p < 128; ++p) acc += dot4f(Wo[p], A4[(size_t)(80 + p) * 64 + lane]);
      } else {
        acc = 0.f;
        #pragma unroll 4
        for (int p = 0; p < 64; ++p) acc += dot4f(Wo[128 + p], A4[(size_t)(16 + p) * 64 + lane]);
      }
      g_outp[kh * 4096 + j * 64 + lane] = acc;
    }
    gbar(g_cnt, ++epoch, tid);
    if (t == TT) {
      if (isBatch && tid < 64) {
        float v = g_outp[tid * 64 + b2] + g_outp[4096 + tid * 64 + b2];
        out[((size_t)b2 * TT + (TT - 1)) * DD + tid] = sigf(v);
      }
      break;
    }

    // ======== phase B: LSTM elementwise + out(t-1) combine (batch-blocks) ========
    if (isBatch) {
      if (tid < HH) {
        const float* gg = g_gates;
        float gi = gg[(size_t)(tid) * 64 + b2]        + gg[131072 + (size_t)(tid) * 64 + b2];
        float gf = gg[(size_t)(512 + tid) * 64 + b2]  + gg[131072 + (size_t)(512 + tid) * 64 + b2];
        float gG = gg[(size_t)(1024 + tid) * 64 + b2] + gg[131072 + (size_t)(1024 + tid) * 64 + b2];
        float go = gg[(size_t)(1536 + tid) * 64 + b2] + gg[131072 + (size_t)(1536 + tid) * 64 + b2];
        float cn = sigf(gf) * s_c[tid] + sigf(gi) * tanhf(gG);
        float hn = sigf(go) * tanhf(cn);
        s_c[tid] = cn;
        Aw(g_A, 320 + tid, b2, hn);
      } else if (t > 0 && tid >= 512 && tid < 576) {
        int j = tid - 512;
        float v = g_outp[j * 64 + b2] + g_outp[4096 + j * 64 + b2];
        out[((size_t)b2 * TT + (t - 1)) * DD + j] = sigf(v);
      }
    }
    gbar(g_cnt, ++epoch, tid);

    // ======== phase C: GEMM2 (all head projections, 1072 rows x splitK2) ========
    if (wid < 2144) {
      int r = __builtin_amdgcn_readfirstlane(wid >> 1);
      int kh = wid & 1;
      const float* Wr;
      float bias = 0.f;
      if (r < 280) {
        Wr = read_W + (size_t)r * 512;
        if (!kh) bias = read_b[r];
      } else {
        Wr = write_W + (size_t)(r - 280) * 512;
        if (!kh) bias = write_b[r - 280];
      }
      const float4* W4 = (const float4*)Wr + kh * 64;
      const float4* A4 = (const float4*)g_A + (size_t)(80 + kh * 64) * 64 + lane;
      float acc = bias;
      #pragma unroll 4
      for (int p = 0; p < 64; ++p) acc += dot4f(W4[p], A4[(size_t)p * 64]);
      g_headp[(size_t)kh * 68608 + (size_t)r * 64 + lane] = acc;
    }
    gbar(g_cnt, ++epoch, tid);

    // ======== phase D: per-batch memory phase ========
    if (isBatch) {
      for (int hd = 0; hd < RR; ++hd) {
        // gather o_r / o_w (sum splitK halves; bias already in kh0)
        if (tid < 70) {
          int r = hd * 70 + tid;
          s_or[tid] = g_headp[(size_t)r * 64 + b2] + g_headp[68608 + (size_t)r * 64 + b2];
        } else if (tid >= 128 && tid < 326) {
          int i = tid - 128;
          int r = 280 + hd * 198 + i;
          s_ow[i] = g_headp[(size_t)r * 64 + b2] + g_headp[68608 + (size_t)r * 64 + b2];
        }
        __syncthreads();
        if (tid < VV) { s_e[tid] = sigf(s_ow[70 + tid]); s_a[tid] = s_ow[134 + tid]; }

        // dual-key dot over own bf16 row (read + write keys in one sweep)
        const uint4* rowp = (const uint4*)(membf + (size_t)tid * VV);
        const float4* orf = (const float4*)s_or;
        const float4* owf = (const float4*)s_ow;
        float dotR = 0.f, dotW = 0.f, kkR = 0.f, kkW = 0.f;
        #pragma unroll
        for (int p = 0; p < 8; ++p) {
          uint4 m = rowp[p];
          float4 ka = orf[2 * p], kb = orf[2 * p + 1];
          float4 wa = owf[2 * p], wb = owf[2 * p + 1];
          kkR += dot4f(ka, ka) + dot4f(kb, kb);
          kkW += dot4f(wa, wa) + dot4f(wb, wb);
          float m0 = bflo(m.x), m1 = bfhi(m.x), m2 = bflo(m.y), m3 = bfhi(m.y);
          float m4 = bflo(m.z), m5 = bfhi(m.z), m6 = bflo(m.w), m7 = bfhi(m.w);
          dotR += m0 * ka.x + m1 * ka.y + m2 * ka.z + m3 * ka.w +
                  m4 * kb.x + m5 * kb.y + m6 * kb.z + m7 * kb.w;
          dotW += m0 * wa.x + m1 * wa.y + m2 * wa.z + m3 * wa.w +
                  m4 * wb.x + m5 * wb.y + m6 * wb.z + m7 * wb.w;
        }
        float na = fmaxf(sqrtf(nrm2), 1e-8f);

        float wR = soft_addr(dotR, kkR, s_or[64], s_or[65], s_or[66], s_or[67],
                             s_or[68], s_or[69], na, s_ws + (size_t)(2 * hd) * NN,
                             s_scr, s_redR, tid, lane, wave);
        s_scr[tid] = wR;   // published for einsum (ordered by W-softmax's syncs)
        float wW = soft_addr(dotW, kkW, s_ow[64], s_ow[65], s_ow[66], s_ow[67],
                             s_ow[68], s_ow[69], na, s_ws + (size_t)(2 * hd + 1) * NN,
                             s_scr, s_redW, tid, lane, wave);

        // einsum partials on pre-erase mem: wave = 64 rows, lane = column
        {
          int base = wave * 64;
          float acc = 0.f;
          #pragma unroll 8
          for (int r = 0; r < 64; ++r)
            acc += s_scr[base + r] * bflo((uint_t)membf[(size_t)(base + r) * VV + lane]);
          s_scr[1024 + wave * 64 + lane] = acc;
        }
        __syncthreads();
        if (tid < VV) {
          float s = 0.f;
          #pragma unroll
          for (int w = 0; w < 16; ++w) s += s_scr[1024 + w * 64 + tid];
          s_reads[hd * VV + tid] = s;
        }
        // erase/add own row (bf16 RMW) + norm update from rounded values
        {
          uint4* rowm = (uint4*)(membf + (size_t)tid * VV);
          const float4* e4 = (const float4*)s_e;
          const float4* a4 = (const float4*)s_a;
          float nacc = 0.f;
          #pragma unroll
          for (int p = 0; p < 8; ++p) {
            uint4 m = rowm[p];
            float4 ev = e4[2 * p], ev2 = e4[2 * p + 1];
            float4 av = a4[2 * p], av2 = a4[2 * p + 1];
            float m0 = bflo(m.x) * (1.f - wW * ev.x) + wW * av.x;
            float m1 = bfhi(m.x) * (1.f - wW * ev.y) + wW * av.y;
            float m2 = bflo(m.y) * (1.f - wW * ev.z) + wW * av.z;
            float m3 = bfhi(m.y) * (1.f - wW * ev.w) + wW * av.w;
            float m4 = bflo(m.z) * (1.f - wW * ev2.x) + wW * av2.x;
            float m5 = bfhi(m.z) * (1.f - wW * ev2.y) + wW * av2.y;
            float m6 = bflo(m.w) * (1.f - wW * ev2.z) + wW * av2.z;
            float m7 = bfhi(m.w) * (1.f - wW * ev2.w) + wW * av2.w;
            uint4 o;
            o.x = (uint_t)bfr(m0) | ((uint_t)bfr(m1) << 16);
            o.y = (uint_t)bfr(m2) | ((uint_t)bfr(m3) << 16);
            o.z = (uint_t)bfr(m4) | ((uint_t)bfr(m5) << 16);
            o.w = (uint_t)bfr(m6) | ((uint_t)bfr(m7) << 16);
            rowm[p] = o;
            float r0 = bflo(o.x), r1 = bfhi(o.x), r2 = bflo(o.y), r3 = bfhi(o.y);
            float r4 = bflo(o.z), r5 = bfhi(o.z), r6 = bflo(o.w), r7 = bfhi(o.w);
            nacc += r0 * r0 + r1 * r1 + r2 * r2 + r3 * r3 +
                    r4 * r4 + r5 * r5 + r6 * r6 + r7 * r7;
          }
          nrm2 = nacc;
        }
      } // hd
      __syncthreads();   // s_reads complete (cross-thread)
      if (tid < RR * VV) Aw(g_A, 64 + tid, b2, s_reads[tid]);
      if (tid < DD && t + 1 < TT)
        Aw(g_A, tid, b2, x[((size_t)b2 * TT + t + 1) * DD + tid]);
    }
    gbar(g_cnt, ++epoch, tid);
  } // t
}

// ---- pre-kernels (every launch; deterministic) ----
__global__ void bias_kernel(const float* __restrict__ bi, const float* __restrict__ bh,
                            float* __restrict__ o) {
  int i = blockIdx.x * 256 + threadIdx.x;
  if (i < 2048) o[i] = bi[i] + bh[i];
}
__global__ void zero_cnt(uint_t* __restrict__ p) {
  if (threadIdx.x < 64) p[threadIdx.x] = 0u;
}

extern "C" void kernel_launch(void* const* d_in, const int* in_sizes, int n_in,
                              void* d_out, int out_size, void* d_ws, size_t ws_size,
                              hipStream_t stream) {
  char* ws = (char*)d_ws;
  ushort_t* g_mem = (ushort_t*)ws;                 // 64*1024*64*2 = 8,388,608
  float* g_A      = (float*)(ws + 8388608);        // 208*64*4*4  =   212,992
  float* g_gates  = (float*)(ws + 8601600);        // 2*2048*64*4 = 1,048,576
  float* g_headp  = (float*)(ws + 9650176);        // 2*1072*64*4 =   548,864
  float* g_outp   = (float*)(ws + 10199040);       // 2*64*64*4   =    32,768
  float* gbias    = (float*)(ws + 10231808);       // 2048*4      =     8,192
  uint_t* g_cnt   = (uint_t*)(ws + 10240000);      //       256

  zero_cnt<<<1, 64, 0, stream>>>(g_cnt);
  bias_kernel<<<8, 256, 0, stream>>>((const float*)d_in[6], (const float*)d_in[7], gbias);

  ntm_fwd<<<dim3(NB), dim3(NT), 0, stream>>>(
      (const float*)d_in[0], (const float*)d_in[1], (const float*)d_in[2],
      (const float*)d_in[3], (const float*)d_in[4], (const float*)d_in[5],
      gbias,
      (const float*)d_in[8], (const float*)d_in[9],
      (const float*)d_in[10], (const float*)d_in[11],
      (const float*)d_in[12], (const float*)d_in[13], (const float*)d_in[14],
      (float*)d_out,
      g_mem, g_A, g_gates, g_headp, g_outp, g_cnt);
}

// Round 7
// 12357.868 us; speedup vs baseline: 1.2486x; 1.2486x over previous
//
#include <hip/hip_runtime.h>
#include <math.h>

#define TT 32
#define DD 64
#define NN 1024
#define VV 64
#define RR 4
#define HH 512
#define NT 1024
#define NB 256
#define APITCH 416      // uints per A row (832 bf16)
#define GPITCH 2112     // g_gates row pitch (2048 gates + 64 out rows)
#define HPITCH 1088     // g_headp row pitch (1072 head rows, padded)

typedef unsigned int uint_t;
typedef unsigned short ushort_t;

__device__ __forceinline__ float sigf(float x) { return 1.0f / (1.0f + __expf(-x)); }
__device__ __forceinline__ float splus(float x) {
  return (x > 0.f) ? (x + log1pf(__expf(-x))) : log1pf(__expf(x));
}
__device__ __forceinline__ float dot4f(float4 a, float4 b) {
  return a.x * b.x + a.y * b.y + a.z * b.z + a.w * b.w;
}
__device__ __forceinline__ ushort_t bfr(float f) {
  uint_t u = __float_as_uint(f);
  return (ushort_t)((u + 0x7fffu + ((u >> 16) & 1u)) >> 16);
}
__device__ __forceinline__ float bflo(uint_t u) { return __uint_as_float(u << 16); }
__device__ __forceinline__ float bfhi(uint_t u) { return __uint_as_float(u & 0xffff0000u); }

// LLC-scoped (device/agent) relaxed atomics: bypass L1/L2 -> coherent across XCDs
// without any cache-wide fences.
__device__ __forceinline__ uint_t aldu(const uint_t* p) {
  return __hip_atomic_load(p, __ATOMIC_RELAXED, __HIP_MEMORY_SCOPE_AGENT);
}
__device__ __forceinline__ float aldf(const float* p) {
  return __hip_atomic_load(p, __ATOMIC_RELAXED, __HIP_MEMORY_SCOPE_AGENT);
}
__device__ __forceinline__ void astf(float* p, float v) {
  __hip_atomic_store(p, v, __ATOMIC_RELAXED, __HIP_MEMORY_SCOPE_AGENT);
}
__device__ __forceinline__ void astu(uint_t* p, uint_t v) {
  __hip_atomic_store(p, v, __ATOMIC_RELAXED, __HIP_MEMORY_SCOPE_AGENT);
}

// Grid barrier: 8-way-split arrival counters (sum-poll, no release hop, no fences).
// __syncthreads drains vmcnt (sc1 stores complete at LLC = agent-visible) before arrival.
__device__ __forceinline__ void gbar(uint_t* cnt, int target, int grp, int tid) {
  __syncthreads();
  if (tid == 0) {
    __hip_atomic_fetch_add(&cnt[grp * 32], 1u, __ATOMIC_RELAXED, __HIP_MEMORY_SCOPE_AGENT);
    uint_t s;
    do {
      s = 0;
      #pragma unroll
      for (int g = 0; g < 8; ++g) s += aldu(&cnt[g * 32]);
      if (s < (uint_t)target) __builtin_amdgcn_s_sleep(1);
    } while (s < (uint_t)target);
  }
  __syncthreads();
}

// Batched GEMM phase: wave = 4 output rows (scalar W stream), lane = batch.
// A staged per-block into LDS bf16 tiles (32k x 64b, 132B pitch), double-buffered.
// Output LDS-transposed so global partial stores/reads are coalesced in [b][row].
template <int WHICH>
__device__ __forceinline__ void gemm_phase(
    int rowgrp, int kq, const float* __restrict__ Wa, const float* __restrict__ Wb,
    const float* __restrict__ Wc, const uint_t* __restrict__ gA,
    float* __restrict__ gdst, int pitch,
    ushort_t* __restrict__ s_tile, float* __restrict__ s_trans, int tid) {
  const int wv = __builtin_amdgcn_readfirstlane(tid >> 6);
  const int lane = tid & 63;
  const int rbase = rowgrp * 64 + 4 * wv;
  int k0, k1;
  if (WHICH == 1) {
    const int ks[7] = {0, 160, 320, 448, 576, 704, 832};
    k0 = ks[kq]; k1 = ks[kq + 1];
  } else {
    k0 = 320 + kq * 128; k1 = k0 + 128;
  }
  float acc0 = 0.f, acc1 = 0.f, acc2 = 0.f, acc3 = 0.f;
  const int sb = tid >> 4, sj = tid & 15;
  uint_t v = aldu(&gA[sb * APITCH + (k0 >> 1) + sj]);
  int p = 0;
  for (int kt = k0; kt < k1; kt += 32) {
    s_tile[p * 2112 + (2 * sj) * 66 + sb] = (ushort_t)(v & 0xffffu);
    s_tile[p * 2112 + (2 * sj + 1) * 66 + sb] = (ushort_t)(v >> 16);
    if (kt + 32 < k1) v = aldu(&gA[sb * APITCH + ((kt + 32) >> 1) + sj]);
    __syncthreads();
    const float *w0 = nullptr, *w1 = nullptr, *w2 = nullptr, *w3 = nullptr;
    bool skip = false;
    if (WHICH == 1) {
      if (rbase < 2048) {            // gate rows: W_ih cols 0..319, W_hh cols 0..511
        if (kt < 320) { w0 = Wa + (size_t)rbase * 320 + kt; w1 = w0 + 320; w2 = w1 + 320; w3 = w2 + 320; }
        else          { w0 = Wb + (size_t)rbase * 512 + (kt - 320); w1 = w0 + 512; w2 = w1 + 512; w3 = w2 + 512; }
      } else {                        // out rows: cols [0..511]=co(A k>=320), [512..767]=reads(A k 64..319)
        const int j = rbase - 2048;
        if (kt < 64) skip = true;
        else if (kt < 320) { w0 = Wc + (size_t)j * 768 + 448 + kt; w1 = w0 + 768; w2 = w1 + 768; w3 = w2 + 768; }
        else               { w0 = Wc + (size_t)j * 768 + (kt - 320); w1 = w0 + 768; w2 = w1 + 768; w3 = w2 + 768; }
      }
    } else {
      if (rbase < 280)       { w0 = Wa + (size_t)rbase * 512 + (kt - 320); w1 = w0 + 512; w2 = w1 + 512; w3 = w2 + 512; }
      else if (rbase < 1072) { w0 = Wb + (size_t)(rbase - 280) * 512 + (kt - 320); w1 = w0 + 512; w2 = w1 + 512; w3 = w2 + 512; }
      else skip = true;
    }
    if (!skip) {
      #pragma unroll
      for (int kk = 0; kk < 32; ++kk) {
        float a = __uint_as_float(((uint_t)s_tile[p * 2112 + kk * 66 + lane]) << 16);
        acc0 = fmaf(w0[kk], a, acc0);
        acc1 = fmaf(w1[kk], a, acc1);
        acc2 = fmaf(w2[kk], a, acc2);
        acc3 = fmaf(w3[kk], a, acc3);
      }
    }
    p ^= 1;
    __syncthreads();
  }
  s_trans[(4 * wv + 0) * 65 + lane] = acc0;
  s_trans[(4 * wv + 1) * 65 + lane] = acc1;
  s_trans[(4 * wv + 2) * 65 + lane] = acc2;
  s_trans[(4 * wv + 3) * 65 + lane] = acc3;
  __syncthreads();
  {
    const int bb = tid >> 4, rq = tid & 15;
    #pragma unroll
    for (int q = 0; q < 4; ++q) {
      float vv = s_trans[(4 * rq + q) * 65 + bb];
      astf(&gdst[(size_t)bb * pitch + rowgrp * 64 + 4 * rq + q], vv);
    }
  }
  __syncthreads();
}

// NTM addressing softmax chain; ws history passed in/out via registers.
__device__ __forceinline__ float soft_addr(
    float dotv, float kk, float b_raw, float g_raw, float s0r, float s1r,
    float s2r, float gam_raw, float na, float wprev,
    float* __restrict__ s_scr, float* __restrict__ s_red,
    int tid, int lane, int wave) {
  float nb = fmaxf(sqrtf(kk), 1e-8f);
  float beta = splus(b_raw);
  float g = sigf(g_raw);
  float mx = fmaxf(s0r, fmaxf(s1r, s2r));
  float e0 = __expf(s0r - mx), e1 = __expf(s1r - mx), e2 = __expf(s2r - mx);
  float sinv = 1.0f / (e0 + e1 + e2);
  float gamma = 1.0f + splus(gam_raw);
  float z = beta * dotv / (na * nb);
  float ee = __expf(z);                 // |z| <= beta: no max-subtract needed
  float v = ee;
  #pragma unroll
  for (int o = 32; o; o >>= 1) v += __shfl_xor(v, o);
  if (lane == 0) s_red[wave] = v;
  __syncthreads();
  float S = 0.f;
  #pragma unroll
  for (int w = 0; w < 16; ++w) S += s_red[w];
  float wgv = g * (ee / S) + (1.0f - g) * wprev;
  s_scr[1024 + tid] = wgv;
  __syncthreads();
  const float* wg = s_scr + 1024;
  float wsn = (e0 * sinv) * wg[(tid + 1023) & 1023] + (e1 * sinv) * wg[tid] +
              (e2 * sinv) * wg[(tid + 1) & 1023];
  float wp = __expf(gamma * __logf(wsn));
  v = wp;
  #pragma unroll
  for (int o = 32; o; o >>= 1) v += __shfl_xor(v, o);
  if (lane == 0) s_red[wave] = v;
  __syncthreads();
  float Z = 0.f;
  #pragma unroll
  for (int w = 0; w < 16; ++w) Z += s_red[w];
  return wp / (Z + 1e-16f);
}

__global__ __launch_bounds__(NT, 4) void ntm_fwd(
    const float* __restrict__ x, const float* __restrict__ mem_bias,
    const float* __restrict__ h_bias, const float* __restrict__ c_bias,
    const float* __restrict__ W_ih, const float* __restrict__ W_hh,
    const float* __restrict__ gbias,
    const float* __restrict__ read_W, const float* __restrict__ read_b,
    const float* __restrict__ write_W, const float* __restrict__ write_b,
    const float* __restrict__ read_init,
    const float* __restrict__ out_W, const float* __restrict__ out_b,
    float* __restrict__ out,
    ushort_t* __restrict__ g_mem, uint_t* __restrict__ g_A,
    float* __restrict__ g_gates, float* __restrict__ g_headp,
    uint_t* __restrict__ g_cnt) {
  const int blk = blockIdx.x;
  const int tid = threadIdx.x;
  const int lane = tid & 63;
  const int wave = tid >> 6;
  const int grp = blk & 7;
  const bool isBatch = (blk < 64);
  const int b2 = blk;

  __shared__ ushort_t s_tile[2 * 2112];          // 8448 B  (A tiles, 132B pitch)
  __shared__ float s_trans[64 * 65];             // 16640 B (GEMM transpose)
  __shared__ alignas(16) float s_scr[2048];      // 8 KB    (w | wg | einsum | staging)
  __shared__ float s_c[HH];
  __shared__ alignas(16) float s_reads[RR * VV];
  __shared__ alignas(16) float s_or[72];
  __shared__ alignas(16) float s_ow[200];
  __shared__ alignas(16) float s_e[VV];
  __shared__ alignas(16) float s_a[VV];
  __shared__ float s_redR[16];
  __shared__ float s_redW[16];

  ushort_t* membf = g_mem + (size_t)b2 * (NN * VV);
  float nrm2 = 0.f;
  float wsr[8];
  #pragma unroll
  for (int i = 0; i < 8; ++i) wsr[i] = 0.f;

  // ---- init: batch-blocks build A_0 (bf16), c, mem (bf16) ----
  if (isBatch) {
    if (tid < 64) s_scr[tid] = x[(size_t)b2 * TT * DD + tid];
    else if (tid < 320) s_scr[tid] = read_init[tid - 64];
    else if (tid < 832) s_scr[tid] = h_bias[tid - 320];
    if (tid < HH) s_c[tid] = c_bias[tid];
    const float4* src = (const float4*)(mem_bias + (size_t)tid * VV);
    uint4* dst = (uint4*)(membf + (size_t)tid * VV);
    float nacc = 0.f;
    #pragma unroll
    for (int p = 0; p < 8; ++p) {
      float4 va = src[2 * p], vb = src[2 * p + 1];
      uint4 o;
      o.x = (uint_t)bfr(va.x) | ((uint_t)bfr(va.y) << 16);
      o.y = (uint_t)bfr(va.z) | ((uint_t)bfr(va.w) << 16);
      o.z = (uint_t)bfr(vb.x) | ((uint_t)bfr(vb.y) << 16);
      o.w = (uint_t)bfr(vb.z) | ((uint_t)bfr(vb.w) << 16);
      dst[p] = o;
      float r0 = bflo(o.x), r1 = bfhi(o.x), r2 = bflo(o.y), r3 = bfhi(o.y);
      float r4 = bflo(o.z), r5 = bfhi(o.z), r6 = bflo(o.w), r7 = bfhi(o.w);
      nacc += r0 * r0 + r1 * r1 + r2 * r2 + r3 * r3 +
              r4 * r4 + r5 * r5 + r6 * r6 + r7 * r7;
    }
    nrm2 = nacc;
    __syncthreads();
    if (tid < 416)
      astu(&g_A[b2 * APITCH + tid],
           (uint_t)bfr(s_scr[2 * tid]) | ((uint_t)bfr(s_scr[2 * tid + 1]) << 16));
  }
  int ep = 1;
  gbar(g_cnt, NB * ep, grp, tid);

  for (int t = 0; t <= TT; ++t) {
    // ---- phase A: GEMM1 (gates_t rows 0..2047 + out_{t-1} rows 2048..2111) ----
    if (blk < 198)
      gemm_phase<1>(blk / 6, blk % 6, W_ih, W_hh, out_W, g_A,
                    g_gates + (size_t)(blk % 6) * 64 * GPITCH, GPITCH,
                    s_tile, s_trans, tid);
    ++ep; gbar(g_cnt, NB * ep, grp, tid);

    if (t == TT) {
      if (isBatch && tid < 64) {
        float acc = out_b[tid];
        #pragma unroll
        for (int q = 0; q < 6; ++q)
          acc += aldf(g_gates + (size_t)q * 64 * GPITCH + (size_t)b2 * GPITCH + 2048 + tid);
        out[((size_t)b2 * TT + (TT - 1)) * DD + tid] = sigf(acc);
      }
      break;
    }

    // ---- phase B: LSTM elementwise + out(t-1) (batch-blocks) ----
    if (isBatch) {
      if (tid < HH) {
        float gi = gbias[tid], gf = gbias[512 + tid];
        float gg2 = gbias[1024 + tid], go = gbias[1536 + tid];
        #pragma unroll
        for (int q = 0; q < 6; ++q) {
          const float* gp = g_gates + (size_t)q * 64 * GPITCH + (size_t)b2 * GPITCH;
          gi += aldf(gp + tid); gf += aldf(gp + 512 + tid);
          gg2 += aldf(gp + 1024 + tid); go += aldf(gp + 1536 + tid);
        }
        float cn = sigf(gf) * s_c[tid] + sigf(gi) * tanhf(gg2);
        float hn = sigf(go) * tanhf(cn);
        s_c[tid] = cn;
        s_scr[tid] = hn;
      } else if (t > 0 && tid >= 512 && tid < 576) {
        int j = tid - 512;
        float acc = out_b[j];
        #pragma unroll
        for (int q = 0; q < 6; ++q)
          acc += aldf(g_gates + (size_t)q * 64 * GPITCH + (size_t)b2 * GPITCH + 2048 + j);
        out[((size_t)b2 * TT + (t - 1)) * DD + j] = sigf(acc);
      }
      __syncthreads();
      if (tid < 256)
        astu(&g_A[b2 * APITCH + 160 + tid],
             (uint_t)bfr(s_scr[2 * tid]) | ((uint_t)bfr(s_scr[2 * tid + 1]) << 16));
    }
    ++ep; gbar(g_cnt, NB * ep, grp, tid);

    // ---- phase C: GEMM2 (head projections, 1072 rows) ----
    if (blk < 68)
      gemm_phase<2>(blk >> 2, blk & 3, read_W, write_W, nullptr, g_A,
                    g_headp + (size_t)(blk & 3) * 64 * HPITCH, HPITCH,
                    s_tile, s_trans, tid);
    ++ep; gbar(g_cnt, NB * ep, grp, tid);

    // ---- phase D: per-batch memory phase ----
    if (isBatch) {
      #pragma unroll
      for (int hd = 0; hd < RR; ++hd) {
        if (tid < 70) {
          int r = hd * 70 + tid;
          float acc = read_b[r];
          #pragma unroll
          for (int q = 0; q < 4; ++q)
            acc += aldf(g_headp + (size_t)q * 64 * HPITCH + (size_t)b2 * HPITCH + r);
          s_or[tid] = acc;
        } else if (tid >= 128 && tid < 326) {
          int i = tid - 128;
          int r = 280 + hd * 198 + i;
          float acc = write_b[hd * 198 + i];
          #pragma unroll
          for (int q = 0; q < 4; ++q)
            acc += aldf(g_headp + (size_t)q * 64 * HPITCH + (size_t)b2 * HPITCH + r);
          s_ow[i] = acc;
        }
        __syncthreads();
        if (tid < VV) { s_e[tid] = sigf(s_ow[70 + tid]); s_a[tid] = s_ow[134 + tid]; }

        // dual-key dot over own row; keep row in regs for the erase
        uint4 rb[8];
        const uint4* rowp = (const uint4*)(membf + (size_t)tid * VV);
        #pragma unroll
        for (int p = 0; p < 8; ++p) rb[p] = rowp[p];
        const float4* orf = (const float4*)s_or;
        const float4* owf = (const float4*)s_ow;
        float dotR = 0.f, dotW = 0.f, kkR = 0.f, kkW = 0.f;
        #pragma unroll
        for (int p = 0; p < 8; ++p) {
          float4 ka = orf[2 * p], kb = orf[2 * p + 1];
          float4 wa = owf[2 * p], wb = owf[2 * p + 1];
          kkR += dot4f(ka, ka) + dot4f(kb, kb);
          kkW += dot4f(wa, wa) + dot4f(wb, wb);
          float m0 = bflo(rb[p].x), m1 = bfhi(rb[p].x), m2 = bflo(rb[p].y), m3 = bfhi(rb[p].y);
          float m4 = bflo(rb[p].z), m5 = bfhi(rb[p].z), m6 = bflo(rb[p].w), m7 = bfhi(rb[p].w);
          dotR += m0 * ka.x + m1 * ka.y + m2 * ka.z + m3 * ka.w +
                  m4 * kb.x + m5 * kb.y + m6 * kb.z + m7 * kb.w;
          dotW += m0 * wa.x + m1 * wa.y + m2 * wa.z + m3 * wa.w +
                  m4 * wb.x + m5 * wb.y + m6 * wb.z + m7 * wb.w;
        }
        float na = fmaxf(sqrtf(nrm2), 1e-8f);
        float wR = soft_addr(dotR, kkR, s_or[64], s_or[65], s_or[66], s_or[67],
                             s_or[68], s_or[69], na, wsr[2 * hd],
                             s_scr, s_redR, tid, lane, wave);
        wsr[2 * hd] = wR;
        s_scr[tid] = wR;
        float wW = soft_addr(dotW, kkW, s_ow[64], s_ow[65], s_ow[66], s_ow[67],
                             s_ow[68], s_ow[69], na, wsr[2 * hd + 1],
                             s_scr, s_redW, tid, lane, wave);
        wsr[2 * hd + 1] = wW;

        // einsum partials on pre-erase mem (wave = 64 rows, lane = column)
        {
          int base = wave * 64;
          float acc = 0.f;
          #pragma unroll 8
          for (int r = 0; r < 64; ++r)
            acc += s_scr[base + r] * bflo((uint_t)membf[(size_t)(base + r) * VV + lane]);
          s_scr[1024 + wave * 64 + lane] = acc;
        }
        __syncthreads();
        if (tid < VV) {
          float s = 0.f;
          #pragma unroll
          for (int w2 = 0; w2 < 16; ++w2) s += s_scr[1024 + w2 * 64 + tid];
          s_reads[hd * VV + tid] = s;
        }
        // erase/add own row from registers + norm update
        {
          uint4* rowm = (uint4*)(membf + (size_t)tid * VV);
          const float4* e4 = (const float4*)s_e;
          const float4* a4 = (const float4*)s_a;
          float nacc = 0.f;
          #pragma unroll
          for (int p = 0; p < 8; ++p) {
            float4 ev = e4[2 * p], ev2 = e4[2 * p + 1];
            float4 av = a4[2 * p], av2 = a4[2 * p + 1];
            float m0 = bflo(rb[p].x) * (1.f - wW * ev.x) + wW * av.x;
            float m1 = bfhi(rb[p].x) * (1.f - wW * ev.y) + wW * av.y;
            float m2 = bflo(rb[p].y) * (1.f - wW * ev.z) + wW * av.z;
            float m3 = bfhi(rb[p].y) * (1.f - wW * ev.w) + wW * av.w;
            float m4 = bflo(rb[p].z) * (1.f - wW * ev2.x) + wW * av2.x;
            float m5 = bfhi(rb[p].z) * (1.f - wW * ev2.y) + wW * av2.y;
            float m6 = bflo(rb[p].w) * (1.f - wW * ev2.z) + wW * av2.z;
            float m7 = bfhi(rb[p].w) * (1.f - wW * ev2.w) + wW * av2.w;
            uint4 o;
            o.x = (uint_t)bfr(m0) | ((uint_t)bfr(m1) << 16);
            o.y = (uint_t)bfr(m2) | ((uint_t)bfr(m3) << 16);
            o.z = (uint_t)bfr(m4) | ((uint_t)bfr(m5) << 16);
            o.w = (uint_t)bfr(m6) | ((uint_t)bfr(m7) << 16);
            rowm[p] = o;
            float r0 = bflo(o.x), r1 = bfhi(o.x), r2 = bflo(o.y), r3 = bfhi(o.y);
            float r4 = bflo(o.z), r5 = bfhi(o.z), r6 = bflo(o.w), r7 = bfhi(o.w);
            nacc += r0 * r0 + r1 * r1 + r2 * r2 + r3 * r3 +
                    r4 * r4 + r5 * r5 + r6 * r6 + r7 * r7;
          }
          nrm2 = nacc;
        }
      } // hd
      __syncthreads();
      if (tid < 128)
        astu(&g_A[b2 * APITCH + 32 + tid],
             (uint_t)bfr(s_reads[2 * tid]) | ((uint_t)bfr(s_reads[2 * tid + 1]) << 16));
      if (t + 1 < TT && tid >= 256 && tid < 320)
        s_scr[1536 + (tid - 256)] = x[((size_t)b2 * TT + t + 1) * DD + (tid - 256)];
      __syncthreads();
      if (t + 1 < TT && tid < 32)
        astu(&g_A[b2 * APITCH + tid],
             (uint_t)bfr(s_scr[1536 + 2 * tid]) | ((uint_t)bfr(s_scr[1536 + 2 * tid + 1]) << 16));
    }
    ++ep; gbar(g_cnt, NB * ep, grp, tid);
  } // t
}

// ---- pre-kernels (every launch; deterministic) ----
__global__ void bias_kernel(const float* __restrict__ bi, const float* __restrict__ bh,
                            float* __restrict__ o) {
  int i = blockIdx.x * 256 + threadIdx.x;
  if (i < 2048) o[i] = bi[i] + bh[i];
}
__global__ void zero_cnt(uint_t* __restrict__ p) {
  if (threadIdx.x < 256) p[threadIdx.x] = 0u;
}

extern "C" void kernel_launch(void* const* d_in, const int* in_sizes, int n_in,
                              void* d_out, int out_size, void* d_ws, size_t ws_size,
                              hipStream_t stream) {
  char* ws = (char*)d_ws;
  ushort_t* g_mem = (ushort_t*)ws;                 // 8,388,608
  uint_t* g_A     = (uint_t*)(ws + 8388608);       //   106,496
  float* g_gates  = (float*)(ws + 8495104);        // 3,244,032
  float* g_headp  = (float*)(ws + 11739136);       // 1,114,112
  float* gbias    = (float*)(ws + 12853248);       //     8,192
  uint_t* g_cnt   = (uint_t*)(ws + 12861440);      //     1,024   (~12.9 MB)

  zero_cnt<<<1, 256, 0, stream>>>(g_cnt);
  bias_kernel<<<8, 256, 0, stream>>>((const float*)d_in[6], (const float*)d_in[7], gbias);

  ntm_fwd<<<dim3(NB), dim3(NT), 0, stream>>>(
      (const float*)d_in[0], (const float*)d_in[1], (const float*)d_in[2],
      (const float*)d_in[3], (const float*)d_in[4], (const float*)d_in[5],
      gbias,
      (const float*)d_in[8], (const float*)d_in[9],
      (const float*)d_in[10], (const float*)d_in[11],
      (const float*)d_in[12], (const float*)d_in[13], (const float*)d_in[14],
      (float*)d_out,
      g_mem, g_A, g_gates, g_headp, g_cnt);
}

// Round 8
// 7406.856 us; speedup vs baseline: 2.0832x; 1.6684x over previous
//
#include <hip/hip_runtime.h>
#include <math.h>

#define TT 32
#define DD 64
#define NN 1024
#define VV 64
#define RR 4
#define HH 512

typedef unsigned int uint_t;
typedef unsigned short ushort_t;

__device__ __forceinline__ float sigf(float x) { return 1.0f / (1.0f + __expf(-x)); }
__device__ __forceinline__ float splus(float x) {
  return (x > 0.f) ? (x + log1pf(__expf(-x))) : log1pf(__expf(x));
}
__device__ __forceinline__ float dot4f(float4 a, float4 b) {
  return a.x * b.x + a.y * b.y + a.z * b.z + a.w * b.w;
}
__device__ __forceinline__ ushort_t bfr(float f) {
  uint_t u = __float_as_uint(f);
  return (ushort_t)((u + 0x7fffu + ((u >> 16) & 1u)) >> 16);
}
__device__ __forceinline__ float bflo(uint_t u) { return __uint_as_float(u << 16); }
__device__ __forceinline__ float bfhi(uint_t u) { return __uint_as_float(u & 0xffff0000u); }
__device__ __forceinline__ uint_t packbf(float a, float b) {
  return (uint_t)bfr(a) | ((uint_t)bfr(b) << 16);
}

// ============ pre-kernels (every launch; deterministic) ============
// Combined gates+out weight, bf16 pairs, row-reordered:
// rows 0..2047: row = h*4+g  <- [W_ih[g*512+h] (k 0..319) | W_hh[g*512+h] (k 320..831)]
// rows 2048..2111: out row j <- [0 (k<64) | out_W[j][512..767] (k 64..319) | out_W[j][0..511] (k>=320)]
__global__ void build_gw(const float* __restrict__ W_ih, const float* __restrict__ W_hh,
                         const float* __restrict__ out_W, uint_t* __restrict__ W2g) {
  int idx = blockIdx.x * 256 + threadIdx.x;           // 2112*416
  if (idx >= 2112 * 416) return;
  int r = idx / 416, kp = idx - r * 416;
  float v[2];
  #pragma unroll
  for (int q = 0; q < 2; ++q) {
    int k = 2 * kp + q;
    float f;
    if (r < 2048) {
      int h = r >> 2, g = r & 3, row = g * 512 + h;
      f = (k < 320) ? W_ih[(size_t)row * 320 + k] : W_hh[(size_t)row * 512 + (k - 320)];
    } else {
      int j = r - 2048;
      if (k < 64) f = 0.f;
      else if (k < 320) f = out_W[(size_t)j * 768 + 512 + (k - 64)];
      else f = out_W[(size_t)j * 768 + (k - 320)];
    }
    v[q] = f;
  }
  W2g[idx] = packbf(v[0], v[1]);
}
// Head weights: rows 0..279 = read_W, 280..1071 = write_W; K=512 (bf16 pairs).
__global__ void build_hw(const float* __restrict__ read_W, const float* __restrict__ write_W,
                         uint_t* __restrict__ W2h) {
  int idx = blockIdx.x * 256 + threadIdx.x;           // 1072*256
  if (idx >= 1072 * 256) return;
  int r = idx >> 8, kp = idx & 255;
  const float* src = (r < 280) ? (read_W + (size_t)r * 512) : (write_W + (size_t)(r - 280) * 512);
  W2h[idx] = packbf(src[2 * kp], src[2 * kp + 1]);
}
__global__ void bias_kernel(const float* __restrict__ bi, const float* __restrict__ bh,
                            float* __restrict__ o) {
  int i = blockIdx.x * 256 + threadIdx.x;
  if (i < 2048) o[i] = bi[i] + bh[i];
}
// init: mem bf16, A2 (x0, read_init, h_bias slot0), c, ws zero. grid 64 x 1024.
__global__ void k0_init(const float* __restrict__ x, const float* __restrict__ mem_bias,
                        const float* __restrict__ h_bias, const float* __restrict__ c_bias,
                        const float* __restrict__ read_init,
                        ushort_t* __restrict__ g_mem, uint_t* __restrict__ A2,
                        float* __restrict__ g_c, float* __restrict__ g_ws) {
  const int b = blockIdx.x, tid = threadIdx.x;
  { // mem row tid -> bf16
    const float4* src = (const float4*)(mem_bias + (size_t)tid * VV);
    uint4* dst = (uint4*)(g_mem + (size_t)b * (NN * VV) + (size_t)tid * VV);
    #pragma unroll
    for (int p = 0; p < 8; ++p) {
      float4 va = src[2 * p], vb = src[2 * p + 1];
      uint4 o;
      o.x = packbf(va.x, va.y); o.y = packbf(va.z, va.w);
      o.z = packbf(vb.x, vb.y); o.w = packbf(vb.z, vb.w);
      dst[p] = o;
    }
  }
  if (tid < 416) {
    float v0, v1;
    if (tid < 32)      { v0 = x[((size_t)b * TT) * DD + 2 * tid]; v1 = x[((size_t)b * TT) * DD + 2 * tid + 1]; }
    else if (tid < 160){ int e = 2 * (tid - 32); v0 = read_init[e]; v1 = read_init[e + 1]; }
    else               { int e = 2 * (tid - 160); v0 = h_bias[e]; v1 = h_bias[e + 1]; }
    A2[(size_t)tid * 64 + b] = packbf(v0, v1);
  }
  if (tid < 512) g_c[(size_t)tid * 64 + b] = c_bias[tid];
  for (int i = tid; i < 8192; i += 1024) g_ws[(size_t)b * 8192 + i] = 0.f;
}

// ============ K1: gates GEMM + LSTM + out(t-1) rows ============
// grid: nGate + nOut blocks x 512 thr. Gate block: 8 h x 64 b. Out block: 8 rows x 64 b.
// par = A h-read slot (h_{t-1}); gates write slot par^1.
__global__ __launch_bounds__(512) void k1_gates(
    int t, int nGate, int par,
    const uint_t* __restrict__ W2g, const float* __restrict__ gbias,
    uint_t* __restrict__ A2, float* __restrict__ g_c,
    const float* __restrict__ out_b, float* __restrict__ out) {
  const int blk = blockIdx.x, tid = threadIdx.x;
  const int lane = tid & 63, u = tid >> 6;
  const bool isGate = (blk < nGate);
  if (!isGate && t == 0) return;
  __shared__ uint_t s_tile[52 * 64];
  __shared__ float s_h[8 * 64];
  float acc0 = 0.f, acc1 = 0.f, acc2 = 0.f, acc3 = 0.f;
  const int hglob = blk * 8 + u;                       // gate block
  const int orow = 2048 + (blk - nGate) * 8 + u;       // out block
  const size_t wbase = isGate ? (size_t)(hglob * 4) * 416 : (size_t)orow * 416;

  for (int c = 0; c < 8; ++c) {
    for (int i = tid; i < 52 * 64; i += 512) {
      int kk = i >> 6, bb = i & 63;
      int kpg = c * 52 + kk;
      int phys = (kpg < 160) ? kpg : kpg + 256 * par;
      s_tile[i] = A2[(size_t)phys * 64 + bb];
    }
    __syncthreads();
    const uint_t* wrow = W2g + wbase + c * 52;
    if (isGate) {
      #pragma unroll 4
      for (int kk = 0; kk < 52; ++kk) {
        uint_t ua = s_tile[kk * 64 + lane];
        float a0 = bflo(ua), a1 = bfhi(ua);
        uint_t w0 = wrow[kk], w1 = wrow[416 + kk], w2 = wrow[832 + kk], w3 = wrow[1248 + kk];
        acc0 += bflo(w0) * a0 + bfhi(w0) * a1;
        acc1 += bflo(w1) * a0 + bfhi(w1) * a1;
        acc2 += bflo(w2) * a0 + bfhi(w2) * a1;
        acc3 += bflo(w3) * a0 + bfhi(w3) * a1;
      }
    } else {
      #pragma unroll 4
      for (int kk = 0; kk < 52; ++kk) {
        uint_t ua = s_tile[kk * 64 + lane];
        uint_t w0 = wrow[kk];
        acc0 += bflo(w0) * bflo(ua) + bfhi(w0) * bfhi(ua);
      }
    }
    __syncthreads();
  }

  if (isGate) {
    float gi = acc0 + gbias[hglob];
    float gf = acc1 + gbias[512 + hglob];
    float gg = acc2 + gbias[1024 + hglob];
    float go = acc3 + gbias[1536 + hglob];
    float c0 = g_c[(size_t)hglob * 64 + lane];
    float cn = sigf(gf) * c0 + sigf(gi) * tanhf(gg);
    float hn = sigf(go) * tanhf(cn);
    g_c[(size_t)hglob * 64 + lane] = cn;
    s_h[u * 64 + lane] = hn;
    __syncthreads();
    if (tid < 256) {
      int q = tid >> 6;                                // pair within block (4 pairs)
      float h0 = s_h[(2 * q) * 64 + lane], h1 = s_h[(2 * q + 1) * 64 + lane];
      int kp = 160 + 256 * (par ^ 1) + blk * 4 + q;    // h pair index hbase/2+q = blk*4+q
      A2[(size_t)kp * 64 + lane] = packbf(h0, h1);
    }
  } else {
    int j = orow - 2048;
    out[((size_t)lane * TT + (t - 1)) * DD + j] = sigf(acc0 + out_b[j]);
  }
}

// ============ K2: head projections GEMM ============
// grid 134 x 512: 8 rows x 64 b per block; K = 512 (h slot wslot).
__global__ __launch_bounds__(512) void k2_heads(
    int wslot, const uint_t* __restrict__ W2h,
    const float* __restrict__ read_b, const float* __restrict__ write_b,
    const uint_t* __restrict__ A2, float* __restrict__ g_headp) {
  const int blk = blockIdx.x, tid = threadIdx.x;
  const int lane = tid & 63, u = tid >> 6;
  const int r = blk * 8 + u;
  __shared__ uint_t s_tile[64 * 64];
  __shared__ float s_tr[8 * 65];
  const int hbase = 160 + 256 * wslot;
  float acc = 0.f;
  const uint_t* wrow = W2h + (size_t)r * 256;
  for (int c = 0; c < 4; ++c) {
    for (int i = tid; i < 64 * 64; i += 512) {
      int kk = i >> 6, bb = i & 63;
      s_tile[i] = A2[(size_t)(hbase + c * 64 + kk) * 64 + bb];
    }
    __syncthreads();
    #pragma unroll 4
    for (int kk = 0; kk < 64; ++kk) {
      uint_t ua = s_tile[kk * 64 + lane];
      uint_t w = wrow[c * 64 + kk];
      acc += bflo(w) * bflo(ua) + bfhi(w) * bfhi(ua);
    }
    __syncthreads();
  }
  acc += (r < 280) ? read_b[r] : write_b[r - 280];
  s_tr[u * 65 + lane] = acc;
  __syncthreads();
  if (tid < 128) {
    int bb = tid & 63, half = tid >> 6;
    float4 v;
    v.x = s_tr[(half * 4 + 0) * 65 + bb];
    v.y = s_tr[(half * 4 + 1) * 65 + bb];
    v.z = s_tr[(half * 4 + 2) * 65 + bb];
    v.w = s_tr[(half * 4 + 3) * 65 + bb];
    *(float4*)(g_headp + (size_t)bb * 1088 + blk * 8 + half * 4) = v;
  }
}

// ============ K3: per-batch memory phase ============
__device__ __forceinline__ float soft_addr(
    float dotv, float kk, float b_raw, float g_raw, float s0r, float s1r,
    float s2r, float gam_raw, float na, float wprev,
    float* __restrict__ s_scr, float* __restrict__ s_red,
    int tid, int lane, int wave) {
  float nb = fmaxf(sqrtf(kk), 1e-8f);
  float beta = splus(b_raw);
  float g = sigf(g_raw);
  float mx = fmaxf(s0r, fmaxf(s1r, s2r));
  float e0 = __expf(s0r - mx), e1 = __expf(s1r - mx), e2 = __expf(s2r - mx);
  float sinv = 1.0f / (e0 + e1 + e2);
  float gamma = 1.0f + splus(gam_raw);
  float z = beta * dotv / (na * nb);
  float ee = __expf(z);                 // |z| <= beta: no max-subtract needed
  float v = ee;
  #pragma unroll
  for (int o = 32; o; o >>= 1) v += __shfl_xor(v, o);
  if (lane == 0) s_red[wave] = v;
  __syncthreads();
  float S = 0.f;
  #pragma unroll
  for (int w = 0; w < 16; ++w) S += s_red[w];
  float wgv = g * (ee / S) + (1.0f - g) * wprev;
  s_scr[1024 + tid] = wgv;
  __syncthreads();
  const float* wg = s_scr + 1024;
  float wsn = (e0 * sinv) * wg[(tid + 1023) & 1023] + (e1 * sinv) * wg[tid] +
              (e2 * sinv) * wg[(tid + 1) & 1023];
  float wp = __expf(gamma * __logf(wsn));
  v = wp;
  #pragma unroll
  for (int o = 32; o; o >>= 1) v += __shfl_xor(v, o);
  if (lane == 0) s_red[wave] = v;
  __syncthreads();
  float Z = 0.f;
  #pragma unroll
  for (int w = 0; w < 16; ++w) Z += s_red[w];
  return wp / (Z + 1e-16f);
}

__global__ __launch_bounds__(1024) void k3_mem(
    int t, const float* __restrict__ x, const float* __restrict__ g_headp,
    ushort_t* __restrict__ g_mem, uint_t* __restrict__ A2,
    float* __restrict__ g_ws) {
  const int b = blockIdx.x, tid = threadIdx.x;
  const int lane = tid & 63, wave = tid >> 6;
  __shared__ alignas(16) float s_scr[2048];
  __shared__ alignas(16) float s_reads[RR * VV];
  __shared__ alignas(16) float s_or[72];
  __shared__ alignas(16) float s_ow[200];
  __shared__ alignas(16) float s_e[VV];
  __shared__ alignas(16) float s_a[VV];
  __shared__ float s_redR[16];
  __shared__ float s_redW[16];
  ushort_t* membf = g_mem + (size_t)b * (NN * VV);
  const float* hp = g_headp + (size_t)b * 1088;

  for (int hd = 0; hd < RR; ++hd) {
    if (tid < 70) s_or[tid] = hp[hd * 70 + tid];
    else if (tid >= 128 && tid < 326) s_ow[tid - 128] = hp[280 + hd * 198 + (tid - 128)];
    __syncthreads();
    if (tid < VV) { s_e[tid] = sigf(s_ow[70 + tid]); s_a[tid] = s_ow[134 + tid]; }

    float wprevR = g_ws[(size_t)(b * 8 + 2 * hd) * 1024 + tid];
    float wprevW = g_ws[(size_t)(b * 8 + 2 * hd + 1) * 1024 + tid];

    // dual-key dot over own row; keep row in regs; inline |row|^2
    uint4 rb[8];
    const uint4* rowp = (const uint4*)(membf + (size_t)tid * VV);
    #pragma unroll
    for (int p = 0; p < 8; ++p) rb[p] = rowp[p];
    const float4* orf = (const float4*)s_or;
    const float4* owf = (const float4*)s_ow;
    float dotR = 0.f, dotW = 0.f, kkR = 0.f, kkW = 0.f, nrm2 = 0.f;
    #pragma unroll
    for (int p = 0; p < 8; ++p) {
      float4 ka = orf[2 * p], kb = orf[2 * p + 1];
      float4 wa = owf[2 * p], wb = owf[2 * p + 1];
      kkR += dot4f(ka, ka) + dot4f(kb, kb);
      kkW += dot4f(wa, wa) + dot4f(wb, wb);
      float m0 = bflo(rb[p].x), m1 = bfhi(rb[p].x), m2 = bflo(rb[p].y), m3 = bfhi(rb[p].y);
      float m4 = bflo(rb[p].z), m5 = bfhi(rb[p].z), m6 = bflo(rb[p].w), m7 = bfhi(rb[p].w);
      nrm2 += m0 * m0 + m1 * m1 + m2 * m2 + m3 * m3 + m4 * m4 + m5 * m5 + m6 * m6 + m7 * m7;
      dotR += m0 * ka.x + m1 * ka.y + m2 * ka.z + m3 * ka.w +
              m4 * kb.x + m5 * kb.y + m6 * kb.z + m7 * kb.w;
      dotW += m0 * wa.x + m1 * wa.y + m2 * wa.z + m3 * wa.w +
              m4 * wb.x + m5 * wb.y + m6 * wb.z + m7 * wb.w;
    }
    float na = fmaxf(sqrtf(nrm2), 1e-8f);
    float wR = soft_addr(dotR, kkR, s_or[64], s_or[65], s_or[66], s_or[67],
                         s_or[68], s_or[69], na, wprevR, s_scr, s_redR, tid, lane, wave);
    g_ws[(size_t)(b * 8 + 2 * hd) * 1024 + tid] = wR;
    s_scr[tid] = wR;
    float wW = soft_addr(dotW, kkW, s_ow[64], s_ow[65], s_ow[66], s_ow[67],
                         s_ow[68], s_ow[69], na, wprevW, s_scr, s_redW, tid, lane, wave);
    g_ws[(size_t)(b * 8 + 2 * hd + 1) * 1024 + tid] = wW;

    // einsum partials on pre-erase mem (wave = 64 rows, lane = column)
    {
      int base = wave * 64;
      float acc = 0.f;
      #pragma unroll 8
      for (int r = 0; r < 64; ++r)
        acc += s_scr[base + r] * bflo((uint_t)membf[(size_t)(base + r) * VV + lane]);
      s_scr[1024 + wave * 64 + lane] = acc;
    }
    __syncthreads();
    if (tid < VV) {
      float s = 0.f;
      #pragma unroll
      for (int w2 = 0; w2 < 16; ++w2) s += s_scr[1024 + w2 * 64 + tid];
      s_reads[hd * VV + tid] = s;
    }
    // erase/add own row from registers
    {
      uint4* rowm = (uint4*)(membf + (size_t)tid * VV);
      const float4* e4 = (const float4*)s_e;
      const float4* a4 = (const float4*)s_a;
      #pragma unroll
      for (int p = 0; p < 8; ++p) {
        float4 ev = e4[2 * p], ev2 = e4[2 * p + 1];
        float4 av = a4[2 * p], av2 = a4[2 * p + 1];
        float m0 = bflo(rb[p].x) * (1.f - wW * ev.x) + wW * av.x;
        float m1 = bfhi(rb[p].x) * (1.f - wW * ev.y) + wW * av.y;
        float m2 = bflo(rb[p].y) * (1.f - wW * ev.z) + wW * av.z;
        float m3 = bfhi(rb[p].y) * (1.f - wW * ev.w) + wW * av.w;
        float m4 = bflo(rb[p].z) * (1.f - wW * ev2.x) + wW * av2.x;
        float m5 = bfhi(rb[p].z) * (1.f - wW * ev2.y) + wW * av2.y;
        float m6 = bflo(rb[p].w) * (1.f - wW * ev2.z) + wW * av2.z;
        float m7 = bfhi(rb[p].w) * (1.f - wW * ev2.w) + wW * av2.w;
        uint4 o;
        o.x = packbf(m0, m1); o.y = packbf(m2, m3);
        o.z = packbf(m4, m5); o.w = packbf(m6, m7);
        rowm[p] = o;
      }
    }
    __syncthreads();
  } // hd

  // publish reads_t and x_{t+1} into A (bf16 pairs)
  if (tid < 128)
    A2[(size_t)(32 + tid) * 64 + b] = packbf(s_reads[2 * tid], s_reads[2 * tid + 1]);
  if (tid < 32 && t + 1 < TT) {
    float v0 = x[((size_t)b * TT + t + 1) * DD + 2 * tid];
    float v1 = x[((size_t)b * TT + t + 1) * DD + 2 * tid + 1];
    A2[(size_t)tid * 64 + b] = packbf(v0, v1);
  }
}

extern "C" void kernel_launch(void* const* d_in, const int* in_sizes, int n_in,
                              void* d_out, int out_size, void* d_ws, size_t ws_size,
                              hipStream_t stream) {
  char* ws = (char*)d_ws;
  ushort_t* g_mem = (ushort_t*)ws;                 // 8,388,608
  uint_t* g_A2    = (uint_t*)(ws + 8388608);       //   172,032
  float* g_c      = (float*)(ws + 8560640);        //   131,072
  float* g_ws     = (float*)(ws + 8691712);        // 2,097,152
  float* g_headp  = (float*)(ws + 10788864);       //   278,528
  uint_t* W2g     = (uint_t*)(ws + 11067392);      // 3,514,368
  uint_t* W2h     = (uint_t*)(ws + 14581760);      // 1,097,728
  float* gbias    = (float*)(ws + 15679488);       //     8,192   (~15.7 MB)

  const float* x        = (const float*)d_in[0];
  const float* mem_bias = (const float*)d_in[1];
  const float* h_bias   = (const float*)d_in[2];
  const float* c_bias   = (const float*)d_in[3];
  const float* W_ih     = (const float*)d_in[4];
  const float* W_hh     = (const float*)d_in[5];
  const float* b_ih     = (const float*)d_in[6];
  const float* b_hh     = (const float*)d_in[7];
  const float* read_W   = (const float*)d_in[8];
  const float* read_b   = (const float*)d_in[9];
  const float* write_W  = (const float*)d_in[10];
  const float* write_b  = (const float*)d_in[11];
  const float* read_init= (const float*)d_in[12];
  const float* out_W    = (const float*)d_in[13];
  const float* out_b    = (const float*)d_in[14];
  float* out = (float*)d_out;

  bias_kernel<<<8, 256, 0, stream>>>(b_ih, b_hh, gbias);
  build_gw<<<3432, 256, 0, stream>>>(W_ih, W_hh, out_W, W2g);
  build_hw<<<1072, 256, 0, stream>>>(read_W, write_W, W2h);
  k0_init<<<64, 1024, 0, stream>>>(x, mem_bias, h_bias, c_bias, read_init,
                                   g_mem, g_A2, g_c, g_ws);
  for (int t = 0; t < TT; ++t) {
    k1_gates<<<72, 512, 0, stream>>>(t, 64, t & 1, W2g, gbias, g_A2, g_c, out_b, out);
    k2_heads<<<134, 512, 0, stream>>>((t + 1) & 1, W2h, read_b, write_b, g_A2, g_headp);
    k3_mem<<<64, 1024, 0, stream>>>(t, x, g_headp, g_mem, g_A2, g_ws);
  }
  // final out row batch: out(t=31) from h_31 (slot 0) + reads_31
  k1_gates<<<8, 512, 0, stream>>>(TT, 0, 0, W2g, gbias, g_A2, g_c, out_b, out);
}